// Round 4
// baseline (456.343 us; speedup 1.0000x reference)
//
#include <hip/hip_runtime.h>

// ComplexScaling: separable bilinear resample, NHWC [N,H,W,2] fp32.
//
// Structural fact: for s == 1.0f and power-of-two H,W the coordinate chain
// ((s*((2j+1)/W - 1) + 1)*W - 1)/2 is EXACT in fp32 (all intermediates are
// dyadic rationals within 24-bit mantissa), so ix == j, iy == i and
// wx1 == wy1 == 0: the op is bitwise out = in. Fast path = pure copy in
// the m13 max-BW shape: 2048 blocks x 256 threads, grid-stride float4,
// ~32 vec4/thread (amortizes block dispatch; R3's one-row-per-block ran
// 32768 tiny blocks and left ~12% of copy BW on the table).
//
// General path (arbitrary theta) shares the same flat grid; (n,i,j) is
// recovered with shifts/masks (H, W are powers of two).

typedef float f32x4 __attribute__((ext_vector_type(4)));

__global__ __launch_bounds__(256) void ComplexScaling_kernel(
    const float* __restrict__ in, const float* __restrict__ theta,
    float* __restrict__ out) {
  constexpr int H = 1024, W = 1024;
  constexpr int NVEC = 16777216;           // N*H*W*2/4 float4s (N=32)
  const float s = 1.0f + theta[0];

  const int tid0 = blockIdx.x * blockDim.x + threadIdx.x;
  const int nthreads = gridDim.x * blockDim.x;     // 524288 -> 32 it/thread

  // ---------- fast path: identity mapping -> pure copy ----------
  // Grid-uniform branch (s is uniform across the grid), no divergence.
  if (s == 1.0f) {
    const f32x4* __restrict__ src = (const f32x4*)in;
    f32x4* __restrict__ dst = (f32x4*)out;
    #pragma unroll 4
    for (int v = tid0; v < NVEC; v += nthreads) {
      dst[v] = src[v];
    }
    return;
  }

  // ---------- general path: separable bilinear gather ----------
  const float Hm1 = (float)(H - 1);
  const float Wm1 = (float)(W - 1);

  for (int v = tid0; v < NVEC; v += nthreads) {
    // each float4 = 2 pixels; decompose flat vec index (pure shifts)
    const int j = (v & (W / 2 - 1)) << 1;    // first pixel column
    const int i = (v >> 9) & (H - 1);        // row
    const int n = v >> 19;                   // batch

    // row (y) coordinate
    float yn  = (2.0f * (float)i + 1.0f) / (float)H - 1.0f;
    float iy  = ((s * yn + 1.0f) * (float)H - 1.0f) * 0.5f;
    float fy0 = floorf(iy);
    float wy1 = iy - fy0;
    float wy0 = 1.0f - wy1;
    float fy1 = fy0 + 1.0f;
    if (!(fy0 >= 0.0f && fy0 <= Hm1)) wy0 = 0.0f;   // zeros padding
    if (!(fy1 >= 0.0f && fy1 <= Hm1)) wy1 = 0.0f;
    int y0 = (int)fminf(fmaxf(fy0, 0.0f), Hm1);
    int y1 = (int)fminf(fmaxf(fy1, 0.0f), Hm1);

    const float* __restrict__ row0 = in + ((long long)(n * H + y0) * W) * 2;
    const float* __restrict__ row1 = in + ((long long)(n * H + y1) * W) * 2;
    const bool need_y1 = (wy1 != 0.0f);

    float vx[2], vy[2];
    #pragma unroll
    for (int p = 0; p < 2; ++p) {
      int jj = j + p;
      float xn  = (2.0f * (float)jj + 1.0f) / (float)W - 1.0f;
      float ix  = ((s * xn + 1.0f) * (float)W - 1.0f) * 0.5f;
      float fx0 = floorf(ix);
      float wx1 = ix - fx0;
      float wx0 = 1.0f - wx1;
      float fx1 = fx0 + 1.0f;
      if (!(fx0 >= 0.0f && fx0 <= Wm1)) wx0 = 0.0f;  // zeros padding
      if (!(fx1 >= 0.0f && fx1 <= Wm1)) wx1 = 0.0f;
      int x0 = (int)fminf(fmaxf(fx0, 0.0f), Wm1);
      int x1 = (int)fminf(fmaxf(fx1, 0.0f), Wm1);

      float ax = 0.0f, ay = 0.0f;
      if (wx0 != 0.0f) {
        const float2 a00 = *(const float2*)(row0 + 2 * x0);
        ax = wx0 * a00.x; ay = wx0 * a00.y;
      }
      if (wx1 != 0.0f) {
        const float2 a01 = *(const float2*)(row0 + 2 * x1);
        ax += wx1 * a01.x; ay += wx1 * a01.y;
      }
      float ox = wy0 * ax, oy = wy0 * ay;

      if (need_y1) {
        float bx = 0.0f, by = 0.0f;
        if (wx0 != 0.0f) {
          const float2 a10 = *(const float2*)(row1 + 2 * x0);
          bx = wx0 * a10.x; by = wx0 * a10.y;
        }
        if (wx1 != 0.0f) {
          const float2 a11 = *(const float2*)(row1 + 2 * x1);
          bx += wx1 * a11.x; by += wx1 * a11.y;
        }
        ox += wy1 * bx; oy += wy1 * by;
      }
      vx[p] = ox; vy[p] = oy;
    }

    f32x4 r;
    r.x = vx[0]; r.y = vy[0]; r.z = vx[1]; r.w = vy[1];
    ((f32x4*)out)[v] = r;
  }
}

extern "C" void kernel_launch(void* const* d_in, const int* in_sizes, int n_in,
                              void* d_out, int out_size, void* d_ws, size_t ws_size,
                              hipStream_t stream) {
  const float* in    = (const float*)d_in[0];
  const float* theta = (const float*)d_in[1];
  float* out = (float*)d_out;

  // m13 max-BW copy shape: 2048 blocks x 256 threads, grid-stride.
  dim3 block(256, 1, 1);
  dim3 grid(2048, 1, 1);
  ComplexScaling_kernel<<<grid, block, 0, stream>>>(in, theta, out);
}